// Round 5
// baseline (444.696 us; speedup 1.0000x reference)
//
#include <hip/hip_runtime.h>
#include <hip/hip_cooperative_groups.h>
#include <cstdint>
#include <cstddef>

namespace cg = cooperative_groups;

#define NB2 2048            // duration buckets (uniform [0,1))
#define NCELL (NB2 * 4)     // buckets x 4 causes
#define NPART 8             // one partial histogram per XCD-ish slice (blockIdx & 7)
#define ALPHA 0.4
#define EPS 1e-8
#define NBLK 512            // cooperative grid: 2 blocks/CU x 256 CU
#define NTHR 512
#define KI 4                // cached items/thread (KI*NBLK*NTHR >= 1M)

// Workspace layout:
//   [0,128)     double acc[9]: [0..3] sum eta over events/cause, [4..7] sum log(denom)/cause, [8] CE sum
//   [128,144)   uint cnt[4]
//   [4096, 4096+8*32KB)  float partial[8][NCELL] (AoS: [b*4+c]), atomically accumulated
//   then 32KB            float suffix[NCELL] (AoS)

#define WRED(v) { for (int o = 32; o; o >>= 1) v += __shfl_down(v, o); }

// Per-item work: head-mean eta -> exp -> LDS hist; event sums; CE on mean logits.
__device__ __forceinline__ void item_work(
    size_t i, const float* __restrict__ log_h, const float* __restrict__ logits,
    const float* __restrict__ dur, const int* __restrict__ ev,
    const int* __restrict__ lab, float* __restrict__ h,
    float& ea0, float& ea1, float& ea2, float& ea3,
    int& c0, int& c1, int& c2, int& c3, float& ce, int& b_out, int& e_out)
{
  const float4* ph = (const float4*)(log_h + i * 32);
  float m0 = 0.f, m1 = 0.f, m2 = 0.f, m3 = 0.f;
#pragma unroll
  for (int m = 0; m < 8; ++m) {
    float4 v = ph[m];
    m0 += v.x; m1 += v.y; m2 += v.z; m3 += v.w;
  }
  float e0 = fminf(fmaxf(m0 * 0.125f, -50.f), 50.f);
  float e1 = fminf(fmaxf(m1 * 0.125f, -50.f), 50.f);
  float e2 = fminf(fmaxf(m2 * 0.125f, -50.f), 50.f);
  float e3 = fminf(fmaxf(m3 * 0.125f, -50.f), 50.f);
  float x0 = __expf(e0), x1 = __expf(e1), x2 = __expf(e2), x3 = __expf(e3);

  float d = dur[i];
  int e = ev[i];
  int b = (int)(d * (float)NB2);
  b = b < 0 ? 0 : (b > NB2 - 1 ? NB2 - 1 : b);
  atomicAdd(&h[0 * NB2 + b], x0);   // SoA: conflict-light
  atomicAdd(&h[1 * NB2 + b], x1);
  atomicAdd(&h[2 * NB2 + b], x2);
  atomicAdd(&h[3 * NB2 + b], x3);

  ea0 += (e == 1) ? e0 : 0.f;  c0 += (e == 1);
  ea1 += (e == 2) ? e1 : 0.f;  c1 += (e == 2);
  ea2 += (e == 3) ? e2 : 0.f;  c2 += (e == 3);
  ea3 += (e == 4) ? e3 : 0.f;  c3 += (e == 4);

  const float4* pl = (const float4*)(logits + i * 40);
  float buf[40];
#pragma unroll
  for (int j = 0; j < 10; ++j) ((float4*)buf)[j] = pl[j];
  float l0 = 0.f, l1 = 0.f, l2 = 0.f, l3 = 0.f, l4 = 0.f;
#pragma unroll
  for (int m = 0; m < 8; ++m) {
    l0 += buf[m * 5 + 0]; l1 += buf[m * 5 + 1]; l2 += buf[m * 5 + 2];
    l3 += buf[m * 5 + 3]; l4 += buf[m * 5 + 4];
  }
  l0 *= 0.125f; l1 *= 0.125f; l2 *= 0.125f; l3 *= 0.125f; l4 *= 0.125f;
  float mx = fmaxf(fmaxf(fmaxf(l0, l1), fmaxf(l2, l3)), l4);
  float se = __expf(l0 - mx) + __expf(l1 - mx) + __expf(l2 - mx) +
             __expf(l3 - mx) + __expf(l4 - mx);
  float lse = __logf(se) + mx;
  int lb = lab[i];
  float lsel = (lb == 0) ? l0 : (lb == 1) ? l1 : (lb == 2) ? l2 : (lb == 3) ? l3 : l4;
  ce += lsel - lse;

  b_out = b; e_out = e;
}

__global__ __launch_bounds__(NTHR, 4) void fused_kernel(
    const float* __restrict__ log_h, const float* __restrict__ logits,
    const float* __restrict__ dur, const int* __restrict__ ev,
    const int* __restrict__ lab, float* __restrict__ partial,
    float* __restrict__ suffix, double* __restrict__ acc,
    unsigned int* __restrict__ cnt, float* __restrict__ out, int N)
{
  cg::grid_group grid = cg::this_grid();
  __shared__ float h[NCELL];          // 32 KB private histogram, SoA; reused by scan
  __shared__ float s_f[5];
  __shared__ unsigned int s_u[4];
  const int t = threadIdx.x;
  const unsigned gtid = blockIdx.x * NTHR + t;
  const unsigned gstride = gridDim.x * NTHR;

  // ---- stage 0: zero global scratch + LDS (replaces hipMemsetAsync) ----
  for (unsigned j = gtid; j < NPART * NCELL; j += gstride) partial[j] = 0.f;
  if (gtid < 9) acc[gtid] = 0.0;
  else if (gtid >= 16 && gtid < 20) cnt[gtid - 16] = 0u;
  for (int j = t; j < NCELL; j += NTHR) h[j] = 0.f;
  if (t < 5) s_f[t] = 0.f;
  if (t < 4) s_u[t] = 0u;
  grid.sync();

  // ---- stage A: merged Cox + CE item loop; cache (b,e) packed in 64-bit reg ----
  float ea0 = 0.f, ea1 = 0.f, ea2 = 0.f, ea3 = 0.f, ce = 0.f;
  int c0 = 0, c1 = 0, c2 = 0, c3 = 0;
  unsigned long long pk = 0ULL;

  for (int k = 0; k < KI; ++k) {
    size_t i = (size_t)gtid + (size_t)k * gstride;
    if (i >= (size_t)N) break;
    int b, e;
    item_work(i, log_h, logits, dur, ev, lab, h,
              ea0, ea1, ea2, ea3, c0, c1, c2, c3, ce, b, e);
    pk |= (unsigned long long)(unsigned)(((b << 3) | e) + 1) << (16 * k);
  }
  // generic overflow (empty when N <= KI*gstride); stage C re-reads for these
  for (size_t i = (size_t)gtid + (size_t)KI * gstride; i < (size_t)N; i += gstride) {
    int b, e;
    item_work(i, log_h, logits, dur, ev, lab, h,
              ea0, ea1, ea2, ea3, c0, c1, c2, c3, ce, b, e);
  }

  WRED(ea0) WRED(ea1) WRED(ea2) WRED(ea3) WRED(ce)
  WRED(c0) WRED(c1) WRED(c2) WRED(c3)
  if ((t & 63) == 0) {
    atomicAdd(&s_f[0], ea0); atomicAdd(&s_f[1], ea1);
    atomicAdd(&s_f[2], ea2); atomicAdd(&s_f[3], ea3);
    atomicAdd(&s_f[4], ce);
    atomicAdd(&s_u[0], (unsigned)c0); atomicAdd(&s_u[1], (unsigned)c1);
    atomicAdd(&s_u[2], (unsigned)c2); atomicAdd(&s_u[3], (unsigned)c3);
  }
  __syncthreads();

  // flush LDS hist (SoA) -> partial[blockIdx&7] (AoS), rotated to decorrelate
  {
    float* part = partial + (size_t)(blockIdx.x & (NPART - 1)) * NCELL;
    const int rot = ((blockIdx.x >> 3) & 31) * 256;
    for (int j = t; j < NCELL; j += NTHR) {
      int jj = (j + rot) & (NCELL - 1);
      float v = h[((jj & 3) << 11) + (jj >> 2)];
      unsafeAtomicAdd(&part[jj], v);
    }
  }
  if (t < 4) {
    unsafeAtomicAdd(&acc[t], (double)s_f[t]);
    atomicAdd(&cnt[t], s_u[t]);
  }
  if (t == 4) unsafeAtomicAdd(&acc[8], (double)s_f[4]);
  grid.sync();

  // ---- stage B: fold partials + inclusive suffix-scan (block 0 only) ----
  if (blockIdx.x == 0) {
    float4* spart = (float4*)h;        // reuse LDS (hist no longer needed)
    const int CH = NB2 / NTHR;         // 4 float4-cells (buckets) per thread
    float4 loc[CH];
    float4 a = make_float4(0.f, 0.f, 0.f, 0.f);
#pragma unroll
    for (int j = 0; j < CH; ++j) {
      float4 s = make_float4(0.f, 0.f, 0.f, 0.f);
#pragma unroll
      for (int p = 0; p < NPART; ++p) {
        float4 v = ((const float4*)(partial + (size_t)p * NCELL))[t * CH + j];
        s.x += v.x; s.y += v.y; s.z += v.z; s.w += v.w;
      }
      loc[j] = s;
      a.x += s.x; a.y += s.y; a.z += s.z; a.w += s.w;
    }
    spart[t] = a;
    __syncthreads();
    for (int off = 1; off < NTHR; off <<= 1) {
      float4 add = make_float4(0.f, 0.f, 0.f, 0.f);
      if (t + off < NTHR) add = spart[t + off];
      __syncthreads();
      float4 cur = spart[t];
      cur.x += add.x; cur.y += add.y; cur.z += add.z; cur.w += add.w;
      spart[t] = cur;
      __syncthreads();
    }
    float4 carry = (t < NTHR - 1) ? spart[t + 1] : make_float4(0.f, 0.f, 0.f, 0.f);
#pragma unroll
    for (int j = CH - 1; j >= 0; --j) {
      carry.x += loc[j].x; carry.y += loc[j].y;
      carry.z += loc[j].z; carry.w += loc[j].w;
      ((float4*)suffix)[t * CH + j] = carry;
    }
  }
  grid.sync();

  // ---- stage C: replay cached (b,e), gather log(denom) ----
  float lg0 = 0.f, lg1 = 0.f, lg2 = 0.f, lg3 = 0.f;
#pragma unroll
  for (int k = 0; k < KI; ++k) {
    unsigned v = (unsigned)(pk >> (16 * k)) & 0xFFFFu;
    if (v) {
      v -= 1u;
      int e = (int)(v & 7u);
      if (e > 0) {
        int b = (int)(v >> 3);
        float lg = __logf(suffix[(size_t)b * 4 + (e - 1)] + (float)EPS);
        lg0 += (e == 1) ? lg : 0.f;
        lg1 += (e == 2) ? lg : 0.f;
        lg2 += (e == 3) ? lg : 0.f;
        lg3 += (e == 4) ? lg : 0.f;
      }
    }
  }
  for (size_t i = (size_t)gtid + (size_t)KI * gstride; i < (size_t)N; i += gstride) {
    int e = ev[i];
    if (e > 0) {
      float d = dur[i];
      int b = (int)(d * (float)NB2);
      b = b < 0 ? 0 : (b > NB2 - 1 ? NB2 - 1 : b);
      float lg = __logf(suffix[(size_t)b * 4 + (e - 1)] + (float)EPS);
      lg0 += (e == 1) ? lg : 0.f;
      lg1 += (e == 2) ? lg : 0.f;
      lg2 += (e == 3) ? lg : 0.f;
      lg3 += (e == 4) ? lg : 0.f;
    }
  }
  WRED(lg0) WRED(lg1) WRED(lg2) WRED(lg3)
  if (t < 4) s_f[t] = 0.f;
  __syncthreads();
  if ((t & 63) == 0) {
    atomicAdd(&s_f[0], lg0); atomicAdd(&s_f[1], lg1);
    atomicAdd(&s_f[2], lg2); atomicAdd(&s_f[3], lg3);
  }
  __syncthreads();
  if (t < 4) unsafeAtomicAdd(&acc[4 + t], (double)s_f[t]);
  grid.sync();

  // ---- stage D: finalize ----
  if (blockIdx.x == 0 && t == 0) {
    double ls = 0.0;
    for (int c = 0; c < 4; ++c) {
      double s = acc[c] - acc[4 + c];
      ls += -s / ((double)cnt[c] + EPS);
    }
    double cem = -acc[8] / (double)N;
    out[0] = (float)(ALPHA * ls + (1.0 - ALPHA) * cem);
  }
}

extern "C" void kernel_launch(void* const* d_in, const int* in_sizes, int n_in,
                              void* d_out, int out_size, void* d_ws, size_t ws_size,
                              hipStream_t stream) {
  const float* log_h  = (const float*)d_in[0];
  const float* logits = (const float*)d_in[1];
  const float* dur    = (const float*)d_in[2];
  const int*   ev     = (const int*)d_in[3];
  const int*   lab    = (const int*)d_in[4];
  const int N = in_sizes[2];

  const size_t cellBytes = (size_t)NCELL * sizeof(float);   // 32 KB
  char* ws = (char*)d_ws;
  double* acc = (double*)ws;
  unsigned int* cnt = (unsigned int*)(ws + 128);
  float* partial = (float*)(ws + 4096);
  float* suffix  = (float*)(ws + 4096 + (size_t)NPART * cellBytes);
  float* outp = (float*)d_out;
  int Nv = N;

  // Cap cooperative grid at actual co-residency (defensive; expected 2 blocks/CU).
  int maxb = 0;
  hipOccupancyMaxActiveBlocksPerMultiprocessor(&maxb, fused_kernel, NTHR, 0);
  int grid = maxb * 256;
  if (grid > NBLK) grid = NBLK;
  if (grid < 1) grid = 1;

  void* args[] = { (void*)&log_h, (void*)&logits, (void*)&dur, (void*)&ev,
                   (void*)&lab, (void*)&partial, (void*)&suffix, (void*)&acc,
                   (void*)&cnt, (void*)&outp, (void*)&Nv };
  hipLaunchCooperativeKernel((void*)fused_kernel, dim3(grid), dim3(NTHR),
                             args, 0, stream);
}